// Round 10
// baseline (116.647 us; speedup 1.0000x reference)
//
#include <hip/hip_runtime.h>
#include <hip/hip_bf16.h>

typedef __hip_bfloat16 bf16;
typedef __bf16 bf16x8 __attribute__((ext_vector_type(8)));
typedef float f32x4 __attribute__((ext_vector_type(4)));
typedef unsigned short u16x8 __attribute__((ext_vector_type(8)));

#define B_SZ   4
#define T_SEQ  2048
#define D_IN   1024
#define D_QKV  64
#define BT     (B_SZ * T_SEQ)   // 8192 rows
#define PSTR   72               // attn p-tile LDS row stride (+8 pad, 16B rows)
#define QS     ((size_t)BT * 192)   // proj partial quarter stride

// async global->LDS DMA, 16B per lane; LDS dest = uniform base + lane*16
#define GLD_LDS(gp, lp) __builtin_amdgcn_global_load_lds(                     \
    (const __attribute__((address_space(1))) void*)(gp),                      \
    (__attribute__((address_space(3))) void*)(lp), 16, 0, 0)

// ---------------------------------------------------------------------------
// Kernel 0: W transpose/convert via LDS, coalesced. Wt[n][k] bf16, n=0..191.
// ---------------------------------------------------------------------------
__global__ __launch_bounds__(256) void wt_prep(
    const float* __restrict__ Wq, const float* __restrict__ Wk,
    const float* __restrict__ Wv, bf16* __restrict__ wt)
{
    __shared__ float ws[64 * 65];
    const int bx = blockIdx.x;
    const int m  = bx >> 4;
    const int k0 = (bx & 15) << 6;
    const float* W = (m == 0) ? Wq : (m == 1) ? Wk : Wv;
    const int tid = threadIdx.x;
    #pragma unroll
    for (int i = 0; i < 16; ++i) {
        const int idx = i * 256 + tid;
        const int kk = idx >> 6, nn = idx & 63;
        ws[kk * 65 + nn] = W[(size_t)(k0 + kk) * D_QKV + nn];
    }
    __syncthreads();
    const int n = tid >> 2, kq = (tid & 3) << 4;
    bf16 tmp[16];
    #pragma unroll
    for (int j = 0; j < 16; ++j)
        tmp[j] = __float2bfloat16(ws[(kq + j) * 65 + n]);
    uint4* dst = (uint4*)(wt + (size_t)(m * 64 + n) * D_IN + k0 + kq);
    dst[0] = ((uint4*)tmp)[0];
    dst[1] = ((uint4*)tmp)[1];
}

// ---------------------------------------------------------------------------
// Kernel A: QKV projection MFMA GEMM, K-split-4. 256 blocks = 64 m-groups
// (128 rows) x 4 K-quarters (256 k). Full N=192 per block -> staged bytes
// 224 KB/block (A 128 KB fp32 + B 96 KB bf16). Double-buffered DMA staging;
// fp32 partials out (summed by combine_qkv).
// LDS swizzle: A phys_ch=(ch+row)&15 (16B ch), B phys_ch=(ch+n)&7.
// ---------------------------------------------------------------------------
__global__ __launch_bounds__(256) void qkv_proj_mfma(
    const float* __restrict__ x, const bf16* __restrict__ wt,
    float* __restrict__ Pp)
{
    __shared__ uint4 As[2][2048];   // 2 x 32 KB: 128 rows x 16 ch
    __shared__ uint4 Bs[2][1536];   // 2 x 24 KB: 192 n x 8 ch

    const int tid  = threadIdx.x;
    const int wave = tid >> 6;
    const int lane = tid & 63;
    const int col  = lane & 15;
    const int quad = lane >> 4;
    const int bx   = blockIdx.x;
    const int m0   = (bx >> 2) * 128;
    const int kq   = bx & 3;

    f32x4 acc[2][12];
    #pragma unroll
    for (int mt = 0; mt < 2; ++mt)
        #pragma unroll
        for (int i = 0; i < 12; ++i) acc[mt][i] = (f32x4){0.f, 0.f, 0.f, 0.f};

    auto stage = [&](int it, int buf) {
        const int k0 = kq * 256 + it * 64;
        #pragma unroll
        for (int j = 0; j < 14; ++j) {
            const int s = wave + j * 4;          // 56 slots x 1 KB
            if (s < 32) {                        // A
                const int o = s * 64 + lane;
                const int r = o >> 4;
                const int ch = ((o & 15) - r) & 15;
                const float* g = x + (size_t)(m0 + r) * D_IN + k0 + ch * 4;
                GLD_LDS(g, &As[buf][s * 64]);
            } else {                             // B
                const int o = (s - 32) * 64 + lane;
                const int n = o >> 3;
                const int ch = ((o & 7) - n) & 7;
                const bf16* g = wt + (size_t)n * D_IN + k0 + ch * 8;
                GLD_LDS(g, &Bs[buf][(s - 32) * 64]);
            }
        }
    };

    stage(0, 0);
    #pragma unroll 1
    for (int it = 0; it < 4; ++it) {
        __syncthreads();                         // staging(it) complete
        if (it + 1 < 4) stage(it + 1, (it + 1) & 1);
        const uint4* Ac = As[it & 1];
        const uint4* Bc = Bs[it & 1];
        #pragma unroll
        for (int h = 0; h < 2; ++h) {            // k-halves of 64
            bf16x8 bf[12];
            #pragma unroll
            for (int i = 0; i < 12; ++i) {
                const int n = i * 16 + col;
                bf[i] = __builtin_bit_cast(bf16x8, Bc[n * 8 + ((h * 4 + quad + n) & 7)]);
            }
            #pragma unroll
            for (int mt = 0; mt < 2; ++mt) {
                const int r = (wave * 2 + mt) * 16 + col;
                const int ca = h * 8 + quad * 2;
                const float4 a0 = ((const float4*)Ac)[r * 16 + ((ca + r) & 15)];
                const float4 a1 = ((const float4*)Ac)[r * 16 + ((ca + 1 + r) & 15)];
                const bf16x8 af = (bf16x8){(__bf16)a0.x, (__bf16)a0.y, (__bf16)a0.z, (__bf16)a0.w,
                                           (__bf16)a1.x, (__bf16)a1.y, (__bf16)a1.z, (__bf16)a1.w};
                #pragma unroll
                for (int i = 0; i < 12; ++i)
                    acc[mt][i] = __builtin_amdgcn_mfma_f32_16x16x32_bf16(af, bf[i], acc[mt][i], 0, 0, 0);
            }
        }
    }

    // fp32 partials, row-major [row][192]
    float* P = Pp + (size_t)kq * QS;
    #pragma unroll
    for (int mt = 0; mt < 2; ++mt) {
        const int rowb = m0 + (wave * 2 + mt) * 16 + quad * 4;
        #pragma unroll
        for (int i = 0; i < 12; ++i) {
            const int n = i * 16 + col;
            #pragma unroll
            for (int rr = 0; rr < 4; ++rr)
                P[(size_t)(rowb + rr) * 192 + n] = acc[mt][i][rr];
        }
    }
}

// ---------------------------------------------------------------------------
// Kernel A2: sum 4 K-quarter partials -> qb/kb row-major bf16, v transposed
// (coalesced via LDS). 256 blocks x 32 rows.
// ---------------------------------------------------------------------------
__global__ __launch_bounds__(256) void combine_qkv(
    const float* __restrict__ Pp, bf16* __restrict__ qb,
    bf16* __restrict__ kb, bf16* __restrict__ vt)
{
    __shared__ float sv[64 * 33];
    const int t0  = blockIdx.x * 32;
    const int tid = threadIdx.x;

    #pragma unroll
    for (int i = 0; i < 16; ++i) {               // q/k: 32 rows x 128 cols
        const int idx = i * 256 + tid;
        const int row = idx >> 7, n = idx & 127;
        const size_t off = (size_t)(t0 + row) * 192 + n;
        const float s = Pp[off] + Pp[QS + off] + Pp[2 * QS + off] + Pp[3 * QS + off];
        const bf16 vq = __float2bfloat16(s);
        if (n < 64) qb[(size_t)(t0 + row) * D_QKV + n] = vq;
        else        kb[(size_t)(t0 + row) * D_QKV + (n - 64)] = vq;
    }
    #pragma unroll
    for (int i = 0; i < 8; ++i) {                // v: 32 rows x 64 d -> LDS^T
        const int idx = i * 256 + tid;
        const int row = idx >> 6, d = idx & 63;
        const size_t off = (size_t)(t0 + row) * 192 + 128 + d;
        sv[d * 33 + row] = Pp[off] + Pp[QS + off] + Pp[2 * QS + off] + Pp[3 * QS + off];
    }
    __syncthreads();
    const int b = t0 >> 11, tl = t0 & (T_SEQ - 1);
    #pragma unroll
    for (int i = 0; i < 8; ++i) {                // vt[b][d][t], coalesced in t
        const int idx = i * 256 + tid;
        const int d = idx >> 5, t = idx & 31;
        vt[(size_t)b * D_QKV * T_SEQ + (size_t)d * T_SEQ + tl + t] =
            __float2bfloat16(sv[d * 33 + t]);
    }
}

// ---------------------------------------------------------------------------
// Kernel B: MFMA flash attention, Q=128/block (2 subtiles/wave), LDS-staged
// K/V shared by all waves+subtiles, no-max softmax, 4-way chunk split.
// 256 blocks = 64 tiles x 4 quarters.
// ---------------------------------------------------------------------------
__global__ __launch_bounds__(256) void attn_kernel(
    const bf16* __restrict__ qb, const bf16* __restrict__ kb,
    const bf16* __restrict__ vt, float* __restrict__ Op, float* __restrict__ lp)
{
    __shared__ uint4 Ks[2][512];                 // 2 x 8 KB
    __shared__ uint4 Vs[2][512];                 // 2 x 8 KB
    __shared__ unsigned short plds[4 * 16 * PSTR];

    const int tid  = threadIdx.x;
    const int wave = tid >> 6;
    const int lane = tid & 63;
    const int col  = lane & 15;
    const int quad = lane >> 4;
    const int bx   = blockIdx.x;
    const int tile    = bx >> 2;                 // 0..63
    const int quarter = bx & 3;
    const int b    = tile >> 4;
    const int lt   = tile & 15;
    const int qg0  = lt * 128;                   // q start within batch
    const int nch  = 2 * lt + 2;                 // causal 64-key chunks

    const bf16* kbp = kb + (size_t)b * T_SEQ * D_QKV;
    const bf16* vtp = vt + (size_t)b * D_QKV * T_SEQ;
    const uint4* q4 = (const uint4*)(qb + (size_t)b * T_SEQ * D_QKV);

    bf16x8 aq[2][2];
    #pragma unroll
    for (int sub = 0; sub < 2; ++sub) {
        const int row = qg0 + sub * 64 + wave * 16 + col;
        aq[sub][0] = __builtin_bit_cast(bf16x8, q4[row * 8 + quad]);
        aq[sub][1] = __builtin_bit_cast(bf16x8, q4[row * 8 + 4 + quad]);
    }

    f32x4 o[2][4];
    float ls[2][4];
    #pragma unroll
    for (int sub = 0; sub < 2; ++sub)
        #pragma unroll
        for (int dt = 0; dt < 4; ++dt) {
            o[sub][dt] = (f32x4){0.f, 0.f, 0.f, 0.f};
            ls[sub][dt] = 0.f;
        }

    unsigned short* pl = plds + wave * 16 * PSTR;
    const u16x8* p8 = (const u16x8*)pl;

    auto stage = [&](int c, int buf) {
        const int kb0 = c * 64;
        #pragma unroll
        for (int j = 0; j < 4; ++j) {
            const int s = wave + j * 4;
            if (s < 8) {                         // K
                const int o2 = s * 64 + lane;
                const int key = o2 >> 3;
                const int ch = ((o2 & 7) - key) & 7;
                const bf16* g = kbp + (size_t)(kb0 + key) * D_QKV + ch * 8;
                GLD_LDS(g, &Ks[buf][s * 64]);
            } else {                             // V
                const int o2 = (s - 8) * 64 + lane;
                const int d = o2 >> 3;
                const int ch = ((o2 & 7) - d) & 7;
                const bf16* g = vtp + (size_t)d * T_SEQ + kb0 + ch * 8;
                GLD_LDS(g, &Vs[buf][(s - 8) * 64]);
            }
        }
    };

    if (quarter < nch) stage(quarter, 0);
    int i = 0;
    for (int c = quarter; c < nch; c += 4, ++i) {
        __syncthreads();
        if (c + 4 < nch) stage(c + 4, (i + 1) & 1);
        const uint4* Kc = Ks[i & 1];
        const uint4* Vc = Vs[i & 1];

        bf16x8 bv0[4], bv1[4];                   // shared by both subtiles
        #pragma unroll
        for (int dt = 0; dt < 4; ++dt) {
            const int dp = dt * 16 + col;
            bv0[dt] = __builtin_bit_cast(bf16x8, Vc[dp * 8 + ((quad + dp) & 7)]);
            bv1[dt] = __builtin_bit_cast(bf16x8, Vc[dp * 8 + ((4 + quad + dp) & 7)]);
        }

        #pragma unroll
        for (int sub = 0; sub < 2; ++sub) {
            if (sub == 0 && c == nch - 1) continue;   // keys entirely above sub0

            f32x4 sc[4];
            #pragma unroll
            for (int nt = 0; nt < 4; ++nt) {
                const int kp = nt * 16 + col;
                const bf16x8 bk0 = __builtin_bit_cast(bf16x8, Kc[kp * 8 + ((quad + kp) & 7)]);
                const bf16x8 bk1 = __builtin_bit_cast(bf16x8, Kc[kp * 8 + ((4 + quad + kp) & 7)]);
                sc[nt] = (f32x4){0.f, 0.f, 0.f, 0.f};
                sc[nt] = __builtin_amdgcn_mfma_f32_16x16x32_bf16(aq[sub][0], bk0, sc[nt], 0, 0, 0);
                sc[nt] = __builtin_amdgcn_mfma_f32_16x16x32_bf16(aq[sub][1], bk1, sc[nt], 0, 0, 0);
            }

            if (c == nch - 2 + sub) {            // diagonal chunk for this subtile
                #pragma unroll
                for (int nt = 0; nt < 4; ++nt) {
                    const int kp = c * 64 + nt * 16 + col;
                    #pragma unroll
                    for (int rr = 0; rr < 4; ++rr)
                        if (kp > qg0 + sub * 64 + wave * 16 + quad * 4 + rr)
                            sc[nt][rr] = -INFINITY;
                }
            }

            #pragma unroll
            for (int nt = 0; nt < 4; ++nt) {
                #pragma unroll
                for (int rr = 0; rr < 4; ++rr) {
                    const float pv = __expf(sc[nt][rr] * 0.125f);
                    ls[sub][rr] += pv;
                    pl[(quad * 4 + rr) * PSTR + nt * 16 + col] =
                        __builtin_bit_cast(unsigned short, __float2bfloat16(pv));
                }
            }
            const bf16x8 pa0 = __builtin_bit_cast(bf16x8, p8[col * 9 + quad]);
            const bf16x8 pa1 = __builtin_bit_cast(bf16x8, p8[col * 9 + 4 + quad]);
            #pragma unroll
            for (int dt = 0; dt < 4; ++dt) {
                o[sub][dt] = __builtin_amdgcn_mfma_f32_16x16x32_bf16(pa0, bv0[dt], o[sub][dt], 0, 0, 0);
                o[sub][dt] = __builtin_amdgcn_mfma_f32_16x16x32_bf16(pa1, bv1[dt], o[sub][dt], 0, 0, 0);
            }
        }
    }

    #pragma unroll
    for (int sub = 0; sub < 2; ++sub)
        #pragma unroll
        for (int rr = 0; rr < 4; ++rr) {
            #pragma unroll
            for (int msk = 1; msk < 16; msk <<= 1)
                ls[sub][rr] += __shfl_xor(ls[sub][rr], msk);
        }

    const int pbase = (tile * 4 + quarter) * 128;
    #pragma unroll
    for (int sub = 0; sub < 2; ++sub) {
        #pragma unroll
        for (int dt = 0; dt < 4; ++dt)
            #pragma unroll
            for (int rr = 0; rr < 4; ++rr)
                Op[(size_t)(pbase + sub * 64 + wave * 16 + quad * 4 + rr) * D_QKV
                   + dt * 16 + col] = o[sub][dt][rr];
        if (col == 0) {
            #pragma unroll
            for (int rr = 0; rr < 4; ++rr)
                lp[pbase + sub * 64 + wave * 16 + quad * 4 + rr] = ls[sub][rr];
        }
    }
}

// ---------------------------------------------------------------------------
// Kernel C: combine 4 linear partials: out = sum(O_k) / sum(l_k).
// ---------------------------------------------------------------------------
__global__ __launch_bounds__(256) void combine_attn(
    const float* __restrict__ Op, const float* __restrict__ lp,
    float* __restrict__ out)
{
    const int idx = blockIdx.x * 256 + threadIdx.x;   // 524288 = 8192*64
    const int qg = idx >> 6, d = idx & 63;
    const int tile = qg >> 7, rr = qg & 127;
    float s = 0.f, l = 0.f;
    #pragma unroll
    for (int k = 0; k < 4; ++k) {
        s += Op[(size_t)((tile * 4 + k) * 128 + rr) * D_QKV + d];
        l += lp[(tile * 4 + k) * 128 + rr];
    }
    out[(size_t)qg * D_QKV + d] = s / l;
}

// ---------------------------------------------------------------------------
extern "C" void kernel_launch(void* const* d_in, const int* in_sizes, int n_in,
                              void* d_out, int out_size, void* d_ws, size_t ws_size,
                              hipStream_t stream) {
    const float* x  = (const float*)d_in[0];
    const float* Wq = (const float*)d_in[1];
    const float* Wk = (const float*)d_in[2];
    const float* Wv = (const float*)d_in[3];
    float* out = (float*)d_out;

    char* ws = (char*)d_ws;
    bf16*  qb = (bf16*)(ws);                          // 1 MB
    bf16*  kb = (bf16*)(ws + (1u << 20));             // 1 MB
    bf16*  vt = (bf16*)(ws + (2u << 20));             // 1 MB
    bf16*  wt = (bf16*)(ws + (3u << 20));             // 384 KB
    float* Pp = (float*)(ws + (4u << 20));            // 25.2 MB (4 quarters)
    float* Op = (float*)(ws + (32u << 20));           // 8 MB
    float* lp = (float*)(ws + (40u << 20));           // 128 KB

    wt_prep<<<48, 256, 0, stream>>>(Wq, Wk, Wv, wt);
    qkv_proj_mfma<<<256, 256, 0, stream>>>(x, wt, Pp);
    combine_qkv<<<256, 256, 0, stream>>>(Pp, qb, kb, vt);
    attn_kernel<<<256, 256, 0, stream>>>(qb, kb, vt, Op, lp);
    combine_attn<<<2048, 256, 0, stream>>>(Op, lp, out);
}

// Round 11
// 115.934 us; speedup vs baseline: 1.0061x; 1.0061x over previous
//
#include <hip/hip_runtime.h>
#include <hip/hip_bf16.h>

typedef __hip_bfloat16 bf16;
typedef __bf16 bf16x8 __attribute__((ext_vector_type(8)));
typedef float f32x4 __attribute__((ext_vector_type(4)));
typedef unsigned short u16x8 __attribute__((ext_vector_type(8)));

#define B_SZ   4
#define T_SEQ  2048
#define D_IN   1024
#define D_QKV  64
#define BT     (B_SZ * T_SEQ)   // 8192 rows
#define PSTR   72               // attn p-tile LDS row stride (+8 pad, 16B rows)

// async global->LDS DMA, 16B per lane; LDS dest = uniform base + lane*16
#define GLD_LDS(gp, lp) __builtin_amdgcn_global_load_lds(                     \
    (const __attribute__((address_space(1))) void*)(gp),                      \
    (__attribute__((address_space(3))) void*)(lp), 16, 0, 0)

// ---------------------------------------------------------------------------
// Kernel 0: W transpose/convert via LDS, coalesced. Wt[n][k] bf16, n=0..191.
// ---------------------------------------------------------------------------
__global__ __launch_bounds__(256) void wt_prep(
    const float* __restrict__ Wq, const float* __restrict__ Wk,
    const float* __restrict__ Wv, bf16* __restrict__ wt)
{
    __shared__ float ws[64 * 65];
    const int bx = blockIdx.x;
    const int m  = bx >> 4;
    const int k0 = (bx & 15) << 6;
    const float* W = (m == 0) ? Wq : (m == 1) ? Wk : Wv;
    const int tid = threadIdx.x;
    #pragma unroll
    for (int i = 0; i < 16; ++i) {
        const int idx = i * 256 + tid;
        const int kk = idx >> 6, nn = idx & 63;
        ws[kk * 65 + nn] = W[(size_t)(k0 + kk) * D_QKV + nn];
    }
    __syncthreads();
    const int n = tid >> 2, kq = (tid & 3) << 4;
    bf16 tmp[16];
    #pragma unroll
    for (int j = 0; j < 16; ++j)
        tmp[j] = __float2bfloat16(ws[(kq + j) * 65 + n]);
    uint4* dst = (uint4*)(wt + (size_t)(m * 64 + n) * D_IN + k0 + kq);
    dst[0] = ((uint4*)tmp)[0];
    dst[1] = ((uint4*)tmp)[1];
}

// ---------------------------------------------------------------------------
// Kernel A (R9-proven): QKV projection MFMA GEMM with LDS-staged operands.
// 256 blocks = 128 m-groups(64 rows) x 2 n-groups(96 cols). K-steps of 64,
// double-buffered global_load_lds; writes qb/kb/vt directly (no partials).
// LDS swizzle: A phys_ch=(ch+row)&15 (16B ch), B phys_ch=(ch+n)&7.
// ---------------------------------------------------------------------------
__global__ __launch_bounds__(256) void qkv_proj_mfma(
    const float* __restrict__ x, const bf16* __restrict__ wt,
    bf16* __restrict__ qb, bf16* __restrict__ kb, bf16* __restrict__ vt)
{
    __shared__ uint4 As[2][1024];   // 2 x 16 KB
    __shared__ uint4 Bs[2][768];    // 2 x 12 KB

    const int tid  = threadIdx.x;
    const int wave = tid >> 6;
    const int lane = tid & 63;
    const int col  = lane & 15;
    const int quad = lane >> 4;
    const int bx   = blockIdx.x;
    const int m0   = (bx >> 1) * 64;
    const int ng   = bx & 1;

    f32x4 acc[6];
    #pragma unroll
    for (int i = 0; i < 6; ++i) acc[i] = (f32x4){0.f, 0.f, 0.f, 0.f};

    auto stage = [&](int it, int buf) {
        const int k0 = it * 64;
        #pragma unroll
        for (int j = 0; j < 7; ++j) {
            const int s = wave + j * 4;          // wave-uniform slot
            if (s < 16) {                        // A: 16 slots x 1KB
                const int c = s * 64 + lane;
                const int r = c >> 4;
                const int ccl = ((c & 15) - r) & 15;
                const float* g = x + (size_t)(m0 + r) * D_IN + k0 + ccl * 4;
                GLD_LDS(g, &As[buf][s * 64]);
            } else {                             // B: 12 slots x 1KB
                const int bs = s - 16;
                const int c = bs * 64 + lane;
                const int n = c >> 3;
                const int ccl = ((c & 7) - n) & 7;
                const bf16* g = wt + (size_t)(ng * 96 + n) * D_IN + k0 + ccl * 8;
                GLD_LDS(g, &Bs[buf][bs * 64]);
            }
        }
    };

    stage(0, 0);
    const int r = wave * 16 + col;               // this lane's A row (local)
    #pragma unroll 1
    for (int it = 0; it < 16; ++it) {
        __syncthreads();                         // staging(it) done, buf free
        if (it + 1 < 16) stage(it + 1, (it + 1) & 1);   // DMA overlaps compute
        const float4* Ac = (const float4*)As[it & 1];
        const uint4*  Bc = Bs[it & 1];
        #pragma unroll
        for (int s = 0; s < 2; ++s) {
            const int ca = s * 8 + quad * 2;
            const float4 a0 = Ac[r * 16 + ((ca + r) & 15)];
            const float4 a1 = Ac[r * 16 + ((ca + 1 + r) & 15)];
            const bf16x8 af = (bf16x8){(__bf16)a0.x, (__bf16)a0.y, (__bf16)a0.z, (__bf16)a0.w,
                                       (__bf16)a1.x, (__bf16)a1.y, (__bf16)a1.z, (__bf16)a1.w};
            #pragma unroll
            for (int i = 0; i < 6; ++i) {
                const int n = i * 16 + col;
                const bf16x8 bfr = __builtin_bit_cast(bf16x8,
                    Bc[n * 8 + ((s * 4 + quad + n) & 7)]);
                acc[i] = __builtin_amdgcn_mfma_f32_16x16x32_bf16(af, bfr, acc[i], 0, 0, 0);
            }
        }
    }

    // epilogue: q/k row-major bf16, v transposed bf16
    const int bb = m0 >> 11;
    const int tl = m0 & (T_SEQ - 1);
    #pragma unroll
    for (int i = 0; i < 6; ++i) {
        const int n = ng * 96 + i * 16 + col;
        #pragma unroll
        for (int rr = 0; rr < 4; ++rr) {
            const int row = m0 + wave * 16 + quad * 4 + rr;
            const bf16 vq = __float2bfloat16(acc[i][rr]);
            if (n < 64)       qb[(size_t)row * D_QKV + n] = vq;
            else if (n < 128) kb[(size_t)row * D_QKV + (n - 64)] = vq;
            else              vt[(size_t)bb * D_QKV * T_SEQ + (size_t)(n - 128) * T_SEQ
                                 + (tl + wave * 16 + quad * 4 + rr)] = vq;
        }
    }
}

// ---------------------------------------------------------------------------
// Kernel B (R10): MFMA flash attention, Q=128/block (2 subtiles/wave),
// LDS-staged K/V shared by all waves+subtiles, no-max softmax, 4-way chunk
// split. 256 blocks = 64 tiles x 4 quarters.
// ---------------------------------------------------------------------------
__global__ __launch_bounds__(256) void attn_kernel(
    const bf16* __restrict__ qb, const bf16* __restrict__ kb,
    const bf16* __restrict__ vt, float* __restrict__ Op, float* __restrict__ lp)
{
    __shared__ uint4 Ks[2][512];                 // 2 x 8 KB
    __shared__ uint4 Vs[2][512];                 // 2 x 8 KB
    __shared__ unsigned short plds[4 * 16 * PSTR];

    const int tid  = threadIdx.x;
    const int wave = tid >> 6;
    const int lane = tid & 63;
    const int col  = lane & 15;
    const int quad = lane >> 4;
    const int bx   = blockIdx.x;
    const int tile    = bx >> 2;                 // 0..63
    const int quarter = bx & 3;
    const int b    = tile >> 4;
    const int lt   = tile & 15;
    const int qg0  = lt * 128;                   // q start within batch
    const int nch  = 2 * lt + 2;                 // causal 64-key chunks

    const bf16* kbp = kb + (size_t)b * T_SEQ * D_QKV;
    const bf16* vtp = vt + (size_t)b * D_QKV * T_SEQ;
    const uint4* q4 = (const uint4*)(qb + (size_t)b * T_SEQ * D_QKV);

    bf16x8 aq[2][2];
    #pragma unroll
    for (int sub = 0; sub < 2; ++sub) {
        const int row = qg0 + sub * 64 + wave * 16 + col;
        aq[sub][0] = __builtin_bit_cast(bf16x8, q4[row * 8 + quad]);
        aq[sub][1] = __builtin_bit_cast(bf16x8, q4[row * 8 + 4 + quad]);
    }

    f32x4 o[2][4];
    float ls[2][4];
    #pragma unroll
    for (int sub = 0; sub < 2; ++sub)
        #pragma unroll
        for (int dt = 0; dt < 4; ++dt) {
            o[sub][dt] = (f32x4){0.f, 0.f, 0.f, 0.f};
            ls[sub][dt] = 0.f;
        }

    unsigned short* pl = plds + wave * 16 * PSTR;
    const u16x8* p8 = (const u16x8*)pl;

    auto stage = [&](int c, int buf) {
        const int kb0 = c * 64;
        #pragma unroll
        for (int j = 0; j < 4; ++j) {
            const int s = wave + j * 4;
            if (s < 8) {                         // K
                const int o2 = s * 64 + lane;
                const int key = o2 >> 3;
                const int ch = ((o2 & 7) - key) & 7;
                const bf16* g = kbp + (size_t)(kb0 + key) * D_QKV + ch * 8;
                GLD_LDS(g, &Ks[buf][s * 64]);
            } else {                             // V
                const int o2 = (s - 8) * 64 + lane;
                const int d = o2 >> 3;
                const int ch = ((o2 & 7) - d) & 7;
                const bf16* g = vtp + (size_t)d * T_SEQ + kb0 + ch * 8;
                GLD_LDS(g, &Vs[buf][(s - 8) * 64]);
            }
        }
    };

    if (quarter < nch) stage(quarter, 0);
    int i = 0;
    for (int c = quarter; c < nch; c += 4, ++i) {
        __syncthreads();
        if (c + 4 < nch) stage(c + 4, (i + 1) & 1);
        const uint4* Kc = Ks[i & 1];
        const uint4* Vc = Vs[i & 1];

        bf16x8 bv0[4], bv1[4];                   // shared by both subtiles
        #pragma unroll
        for (int dt = 0; dt < 4; ++dt) {
            const int dp = dt * 16 + col;
            bv0[dt] = __builtin_bit_cast(bf16x8, Vc[dp * 8 + ((quad + dp) & 7)]);
            bv1[dt] = __builtin_bit_cast(bf16x8, Vc[dp * 8 + ((4 + quad + dp) & 7)]);
        }

        #pragma unroll
        for (int sub = 0; sub < 2; ++sub) {
            if (sub == 0 && c == nch - 1) continue;   // keys entirely above sub0

            f32x4 sc[4];
            #pragma unroll
            for (int nt = 0; nt < 4; ++nt) {
                const int kp = nt * 16 + col;
                const bf16x8 bk0 = __builtin_bit_cast(bf16x8, Kc[kp * 8 + ((quad + kp) & 7)]);
                const bf16x8 bk1 = __builtin_bit_cast(bf16x8, Kc[kp * 8 + ((4 + quad + kp) & 7)]);
                sc[nt] = (f32x4){0.f, 0.f, 0.f, 0.f};
                sc[nt] = __builtin_amdgcn_mfma_f32_16x16x32_bf16(aq[sub][0], bk0, sc[nt], 0, 0, 0);
                sc[nt] = __builtin_amdgcn_mfma_f32_16x16x32_bf16(aq[sub][1], bk1, sc[nt], 0, 0, 0);
            }

            if (c == nch - 2 + sub) {            // diagonal chunk for this subtile
                #pragma unroll
                for (int nt = 0; nt < 4; ++nt) {
                    const int kp = c * 64 + nt * 16 + col;
                    #pragma unroll
                    for (int rr = 0; rr < 4; ++rr)
                        if (kp > qg0 + sub * 64 + wave * 16 + quad * 4 + rr)
                            sc[nt][rr] = -INFINITY;
                }
            }

            #pragma unroll
            for (int nt = 0; nt < 4; ++nt) {
                #pragma unroll
                for (int rr = 0; rr < 4; ++rr) {
                    const float pv = __expf(sc[nt][rr] * 0.125f);
                    ls[sub][rr] += pv;
                    pl[(quad * 4 + rr) * PSTR + nt * 16 + col] =
                        __builtin_bit_cast(unsigned short, __float2bfloat16(pv));
                }
            }
            const bf16x8 pa0 = __builtin_bit_cast(bf16x8, p8[col * 9 + quad]);
            const bf16x8 pa1 = __builtin_bit_cast(bf16x8, p8[col * 9 + 4 + quad]);
            #pragma unroll
            for (int dt = 0; dt < 4; ++dt) {
                o[sub][dt] = __builtin_amdgcn_mfma_f32_16x16x32_bf16(pa0, bv0[dt], o[sub][dt], 0, 0, 0);
                o[sub][dt] = __builtin_amdgcn_mfma_f32_16x16x32_bf16(pa1, bv1[dt], o[sub][dt], 0, 0, 0);
            }
        }
    }

    #pragma unroll
    for (int sub = 0; sub < 2; ++sub)
        #pragma unroll
        for (int rr = 0; rr < 4; ++rr) {
            #pragma unroll
            for (int msk = 1; msk < 16; msk <<= 1)
                ls[sub][rr] += __shfl_xor(ls[sub][rr], msk);
        }

    const int pbase = (tile * 4 + quarter) * 128;
    #pragma unroll
    for (int sub = 0; sub < 2; ++sub) {
        #pragma unroll
        for (int dt = 0; dt < 4; ++dt)
            #pragma unroll
            for (int rr = 0; rr < 4; ++rr)
                Op[(size_t)(pbase + sub * 64 + wave * 16 + quad * 4 + rr) * D_QKV
                   + dt * 16 + col] = o[sub][dt][rr];
        if (col == 0) {
            #pragma unroll
            for (int rr = 0; rr < 4; ++rr)
                lp[pbase + sub * 64 + wave * 16 + quad * 4 + rr] = ls[sub][rr];
        }
    }
}

// ---------------------------------------------------------------------------
// Kernel C: combine 4 linear partials: out = sum(O_k) / sum(l_k).
// ---------------------------------------------------------------------------
__global__ __launch_bounds__(256) void combine_attn(
    const float* __restrict__ Op, const float* __restrict__ lp,
    float* __restrict__ out)
{
    const int idx = blockIdx.x * 256 + threadIdx.x;   // 524288 = 8192*64
    const int qg = idx >> 6, d = idx & 63;
    const int tile = qg >> 7, rr = qg & 127;
    float s = 0.f, l = 0.f;
    #pragma unroll
    for (int k = 0; k < 4; ++k) {
        s += Op[(size_t)((tile * 4 + k) * 128 + rr) * D_QKV + d];
        l += lp[(tile * 4 + k) * 128 + rr];
    }
    out[(size_t)qg * D_QKV + d] = s / l;
}

// ---------------------------------------------------------------------------
extern "C" void kernel_launch(void* const* d_in, const int* in_sizes, int n_in,
                              void* d_out, int out_size, void* d_ws, size_t ws_size,
                              hipStream_t stream) {
    const float* x  = (const float*)d_in[0];
    const float* Wq = (const float*)d_in[1];
    const float* Wk = (const float*)d_in[2];
    const float* Wv = (const float*)d_in[3];
    float* out = (float*)d_out;

    char* ws = (char*)d_ws;
    bf16*  qb = (bf16*)(ws);                          // 1 MB
    bf16*  kb = (bf16*)(ws + (1u << 20));             // 1 MB
    bf16*  vt = (bf16*)(ws + (2u << 20));             // 1 MB
    bf16*  wt = (bf16*)(ws + (3u << 20));             // 384 KB
    float* Op = (float*)(ws + (4u << 20));            // 8 MB
    float* lp = (float*)(ws + (12u << 20));           // 128 KB

    wt_prep<<<48, 256, 0, stream>>>(Wq, Wk, Wv, wt);
    qkv_proj_mfma<<<256, 256, 0, stream>>>(x, wt, qb, kb, vt);
    attn_kernel<<<256, 256, 0, stream>>>(qb, kb, vt, Op, lp);
    combine_attn<<<2048, 256, 0, stream>>>(Op, lp, out);
}

// Round 12
// 109.910 us; speedup vs baseline: 1.0613x; 1.0548x over previous
//
#include <hip/hip_runtime.h>
#include <hip/hip_bf16.h>

typedef __hip_bfloat16 bf16;
typedef __bf16 bf16x8 __attribute__((ext_vector_type(8)));
typedef float f32x4 __attribute__((ext_vector_type(4)));
typedef unsigned short u16x8 __attribute__((ext_vector_type(8)));

#define B_SZ   4
#define T_SEQ  2048
#define D_IN   1024
#define D_QKV  64
#define BT     (B_SZ * T_SEQ)   // 8192 rows
#define PSTR   72               // attn p-tile LDS row stride (+8 pad, 16B rows)

// async global->LDS DMA, 16B per lane; LDS dest = uniform base + lane*16
#define GLD_LDS(gp, lp) __builtin_amdgcn_global_load_lds(                     \
    (const __attribute__((address_space(1))) void*)(gp),                      \
    (__attribute__((address_space(3))) void*)(lp), 16, 0, 0)

// ---------------------------------------------------------------------------
// Kernel 0: W transpose/convert via LDS, coalesced. Wt[n][k] bf16, n=0..191.
// ---------------------------------------------------------------------------
__global__ __launch_bounds__(256) void wt_prep(
    const float* __restrict__ Wq, const float* __restrict__ Wk,
    const float* __restrict__ Wv, bf16* __restrict__ wt)
{
    __shared__ float ws[64 * 65];
    const int bx = blockIdx.x;
    const int m  = bx >> 4;
    const int k0 = (bx & 15) << 6;
    const float* W = (m == 0) ? Wq : (m == 1) ? Wk : Wv;
    const int tid = threadIdx.x;
    #pragma unroll
    for (int i = 0; i < 16; ++i) {
        const int idx = i * 256 + tid;
        const int kk = idx >> 6, nn = idx & 63;
        ws[kk * 65 + nn] = W[(size_t)(k0 + kk) * D_QKV + nn];
    }
    __syncthreads();
    const int n = tid >> 2, kq = (tid & 3) << 4;
    bf16 tmp[16];
    #pragma unroll
    for (int j = 0; j < 16; ++j)
        tmp[j] = __float2bfloat16(ws[(kq + j) * 65 + n]);
    uint4* dst = (uint4*)(wt + (size_t)(m * 64 + n) * D_IN + k0 + kq);
    dst[0] = ((uint4*)tmp)[0];
    dst[1] = ((uint4*)tmp)[1];
}

// ---------------------------------------------------------------------------
// Kernel A: QKV projection MFMA GEMM with LDS-staged operands (dedup across
// waves -> minimal per-CU vmem-pipe bytes). 256 blocks = 128 m-groups(64 rows)
// x 2 n-groups(96 cols). K-steps of 64, double-buffered global_load_lds.
// LDS swizzle: A phys_ch=(ch+row)&15 (16B ch), B phys_ch=(ch+n)&7.
// Byte-optimal n-split: min over ns of 32*ns + 96/ns MB -> ns=2 (this).
// ---------------------------------------------------------------------------
__global__ __launch_bounds__(256) void qkv_proj_mfma(
    const float* __restrict__ x, const bf16* __restrict__ wt,
    bf16* __restrict__ qb, bf16* __restrict__ kb, bf16* __restrict__ vt)
{
    __shared__ uint4 As[2][1024];   // 2 x 16 KB
    __shared__ uint4 Bs[2][768];    // 2 x 12 KB

    const int tid  = threadIdx.x;
    const int wave = tid >> 6;
    const int lane = tid & 63;
    const int col  = lane & 15;
    const int quad = lane >> 4;
    const int bx   = blockIdx.x;
    const int m0   = (bx >> 1) * 64;
    const int ng   = bx & 1;

    f32x4 acc[6];
    #pragma unroll
    for (int i = 0; i < 6; ++i) acc[i] = (f32x4){0.f, 0.f, 0.f, 0.f};

    auto stage = [&](int it, int buf) {
        const int k0 = it * 64;
        #pragma unroll
        for (int j = 0; j < 7; ++j) {
            const int s = wave + j * 4;          // wave-uniform slot
            if (s < 16) {                        // A: 16 slots x 1KB
                const int c = s * 64 + lane;
                const int r = c >> 4;
                const int ccl = ((c & 15) - r) & 15;
                const float* g = x + (size_t)(m0 + r) * D_IN + k0 + ccl * 4;
                GLD_LDS(g, &As[buf][s * 64]);
            } else {                             // B: 12 slots x 1KB
                const int bs = s - 16;
                const int c = bs * 64 + lane;
                const int n = c >> 3;
                const int ccl = ((c & 7) - n) & 7;
                const bf16* g = wt + (size_t)(ng * 96 + n) * D_IN + k0 + ccl * 8;
                GLD_LDS(g, &Bs[buf][bs * 64]);
            }
        }
    };

    stage(0, 0);
    const int r = wave * 16 + col;               // this lane's A row (local)
    #pragma unroll 1
    for (int it = 0; it < 16; ++it) {
        __syncthreads();                         // staging(it) done, buf free
        if (it + 1 < 16) stage(it + 1, (it + 1) & 1);   // DMA overlaps compute
        const float4* Ac = (const float4*)As[it & 1];
        const uint4*  Bc = Bs[it & 1];
        #pragma unroll
        for (int s = 0; s < 2; ++s) {
            const int ca = s * 8 + quad * 2;
            const float4 a0 = Ac[r * 16 + ((ca + r) & 15)];
            const float4 a1 = Ac[r * 16 + ((ca + 1 + r) & 15)];
            const bf16x8 af = (bf16x8){(__bf16)a0.x, (__bf16)a0.y, (__bf16)a0.z, (__bf16)a0.w,
                                       (__bf16)a1.x, (__bf16)a1.y, (__bf16)a1.z, (__bf16)a1.w};
            #pragma unroll
            for (int i = 0; i < 6; ++i) {
                const int n = i * 16 + col;
                const bf16x8 bfr = __builtin_bit_cast(bf16x8,
                    Bc[n * 8 + ((s * 4 + quad + n) & 7)]);
                acc[i] = __builtin_amdgcn_mfma_f32_16x16x32_bf16(af, bfr, acc[i], 0, 0, 0);
            }
        }
    }

    // epilogue: q/k row-major bf16, v transposed bf16
    const int bb = m0 >> 11;
    const int tl = m0 & (T_SEQ - 1);
    #pragma unroll
    for (int i = 0; i < 6; ++i) {
        const int n = ng * 96 + i * 16 + col;
        #pragma unroll
        for (int rr = 0; rr < 4; ++rr) {
            const int row = m0 + wave * 16 + quad * 4 + rr;
            const bf16 vq = __float2bfloat16(acc[i][rr]);
            if (n < 64)       qb[(size_t)row * D_QKV + n] = vq;
            else if (n < 128) kb[(size_t)row * D_QKV + (n - 64)] = vq;
            else              vt[(size_t)bb * D_QKV * T_SEQ + (size_t)(n - 128) * T_SEQ
                                 + (tl + wave * 16 + quad * 4 + rr)] = vq;
        }
    }
}

// ---------------------------------------------------------------------------
// Kernel B: MFMA flash attention, LDS-staged K/V shared by all 4 waves
// (64 q-rows per block), no-max softmax (scores bounded -> linear partials),
// 4-way chunk split across blocks. 512 blocks (2/CU: barrier bubbles of one
// block overlap the other's compute -- measured faster than 256-block Q=128).
// ---------------------------------------------------------------------------
__global__ __launch_bounds__(256) void attn_kernel(
    const bf16* __restrict__ qb, const bf16* __restrict__ kb,
    const bf16* __restrict__ vt, float* __restrict__ Op, float* __restrict__ lp)
{
    __shared__ uint4 Ks[2][512];                 // 2 x 8 KB
    __shared__ uint4 Vs[2][512];                 // 2 x 8 KB
    __shared__ unsigned short plds[4 * 16 * PSTR];

    const int tid  = threadIdx.x;
    const int wave = tid >> 6;
    const int lane = tid & 63;
    const int col  = lane & 15;
    const int quad = lane >> 4;
    const int bx   = blockIdx.x;
    const int tile    = (bx < 256) ? (127 - (bx >> 2)) : ((bx - 256) >> 2);
    const int quarter = bx & 3;
    const int b    = tile >> 5;
    const int qloc = (tile & 31) * 64;           // q start within batch
    const int nch  = (tile & 31) + 1;            // causal chunk count

    const bf16* kbp = kb + (size_t)b * T_SEQ * D_QKV;
    const bf16* vtp = vt + (size_t)b * D_QKV * T_SEQ;
    const uint4* q4 = (const uint4*)(qb + (size_t)b * T_SEQ * D_QKV);

    const bf16x8 aq0 = __builtin_bit_cast(bf16x8, q4[(qloc + wave * 16 + col) * 8 + quad]);
    const bf16x8 aq1 = __builtin_bit_cast(bf16x8, q4[(qloc + wave * 16 + col) * 8 + 4 + quad]);

    f32x4 o[4];
    float ls[4];
    #pragma unroll
    for (int dt = 0; dt < 4; ++dt) o[dt] = (f32x4){0.f, 0.f, 0.f, 0.f};
    #pragma unroll
    for (int rr = 0; rr < 4; ++rr) ls[rr] = 0.f;

    unsigned short* pl = plds + wave * 16 * PSTR;
    const u16x8* p8 = (const u16x8*)pl;

    auto stage = [&](int c, int buf) {
        const int kb0 = c * 64;
        #pragma unroll
        for (int j = 0; j < 4; ++j) {
            const int s = wave + j * 4;
            if (s < 8) {                         // K: 8 slots
                const int ch = s * 64 + lane;
                const int key = ch >> 3;
                const int ccl = ((ch & 7) - key) & 7;
                const bf16* g = kbp + (size_t)(kb0 + key) * D_QKV + ccl * 8;
                GLD_LDS(g, &Ks[buf][s * 64]);
            } else {                             // V: 8 slots
                const int vs = s - 8;
                const int ch = vs * 64 + lane;
                const int d = ch >> 3;
                const int ccl = ((ch & 7) - d) & 7;
                const bf16* g = vtp + (size_t)d * T_SEQ + kb0 + ccl * 8;
                GLD_LDS(g, &Vs[buf][vs * 64]);
            }
        }
    };

    if (quarter < nch) stage(quarter, 0);
    int i = 0;
    for (int c = quarter; c < nch; c += 4, ++i) {
        __syncthreads();
        if (c + 4 < nch) stage(c + 4, (i + 1) & 1);
        const uint4* Kc = Ks[i & 1];
        const uint4* Vc = Vs[i & 1];

        // QK^T from LDS K
        f32x4 sc[4];
        #pragma unroll
        for (int nt = 0; nt < 4; ++nt) {
            const int kp = nt * 16 + col;
            const bf16x8 bk0 = __builtin_bit_cast(bf16x8, Kc[kp * 8 + ((quad + kp) & 7)]);
            const bf16x8 bk1 = __builtin_bit_cast(bf16x8, Kc[kp * 8 + ((4 + quad + kp) & 7)]);
            sc[nt] = (f32x4){0.f, 0.f, 0.f, 0.f};
            sc[nt] = __builtin_amdgcn_mfma_f32_16x16x32_bf16(aq0, bk0, sc[nt], 0, 0, 0);
            sc[nt] = __builtin_amdgcn_mfma_f32_16x16x32_bf16(aq1, bk1, sc[nt], 0, 0, 0);
        }

        // causal mask (only the diagonal chunk)
        if (c == nch - 1) {
            #pragma unroll
            for (int nt = 0; nt < 4; ++nt) {
                const int kp = c * 64 + nt * 16 + col;
                #pragma unroll
                for (int rr = 0; rr < 4; ++rr)
                    if (kp > qloc + wave * 16 + quad * 4 + rr) sc[nt][rr] = -INFINITY;
            }
        }

        // P = exp(s/8) raw; per-lane l accumulation
        #pragma unroll
        for (int nt = 0; nt < 4; ++nt) {
            #pragma unroll
            for (int rr = 0; rr < 4; ++rr) {
                const float pv = __expf(sc[nt][rr] * 0.125f);
                ls[rr] += pv;
                pl[(quad * 4 + rr) * PSTR + nt * 16 + col] =
                    __builtin_bit_cast(unsigned short, __float2bfloat16(pv));
            }
        }

        // P A-fragments (same-wave RAW via lgkmcnt)
        const bf16x8 pa0 = __builtin_bit_cast(bf16x8, p8[col * 9 + quad]);
        const bf16x8 pa1 = __builtin_bit_cast(bf16x8, p8[col * 9 + 4 + quad]);

        // O += P * V from LDS V
        #pragma unroll
        for (int dt = 0; dt < 4; ++dt) {
            const int dp = dt * 16 + col;
            const bf16x8 bv0 = __builtin_bit_cast(bf16x8, Vc[dp * 8 + ((quad + dp) & 7)]);
            const bf16x8 bv1 = __builtin_bit_cast(bf16x8, Vc[dp * 8 + ((4 + quad + dp) & 7)]);
            o[dt] = __builtin_amdgcn_mfma_f32_16x16x32_bf16(pa0, bv0, o[dt], 0, 0, 0);
            o[dt] = __builtin_amdgcn_mfma_f32_16x16x32_bf16(pa1, bv1, o[dt], 0, 0, 0);
        }
    }

    // l reduction over the 16 key-lanes
    #pragma unroll
    for (int rr = 0; rr < 4; ++rr) {
        #pragma unroll
        for (int msk = 1; msk < 16; msk <<= 1)
            ls[rr] += __shfl_xor(ls[rr], msk);
    }

    // store linear partials (Op, lp); combined by combine_attn
    const int pbase = (tile * 4 + quarter) * 64 + wave * 16;
    #pragma unroll
    for (int dt = 0; dt < 4; ++dt)
        #pragma unroll
        for (int rr = 0; rr < 4; ++rr)
            Op[(size_t)(pbase + quad * 4 + rr) * D_QKV + dt * 16 + col] = o[dt][rr];
    if (col == 0) {
        #pragma unroll
        for (int rr = 0; rr < 4; ++rr)
            lp[pbase + quad * 4 + rr] = ls[rr];
    }
}

// ---------------------------------------------------------------------------
// Kernel C: combine 4 linear partials: out = sum(O_k) / sum(l_k).
// ---------------------------------------------------------------------------
__global__ __launch_bounds__(256) void combine_attn(
    const float* __restrict__ Op, const float* __restrict__ lp,
    float* __restrict__ out)
{
    const int idx = blockIdx.x * 256 + threadIdx.x;   // 524288 = 8192*64
    const int qg = idx >> 6, d = idx & 63;
    const int tile = qg >> 6, qq = qg & 63;
    float s = 0.f, l = 0.f;
    #pragma unroll
    for (int k = 0; k < 4; ++k) {
        s += Op[(size_t)((tile * 4 + k) * 64 + qq) * D_QKV + d];
        l += lp[(tile * 4 + k) * 64 + qq];
    }
    out[(size_t)qg * D_QKV + d] = s / l;
}

// ---------------------------------------------------------------------------
extern "C" void kernel_launch(void* const* d_in, const int* in_sizes, int n_in,
                              void* d_out, int out_size, void* d_ws, size_t ws_size,
                              hipStream_t stream) {
    const float* x  = (const float*)d_in[0];
    const float* Wq = (const float*)d_in[1];
    const float* Wk = (const float*)d_in[2];
    const float* Wv = (const float*)d_in[3];
    float* out = (float*)d_out;

    char* ws = (char*)d_ws;
    bf16*  qb = (bf16*)(ws);                          // 1 MB
    bf16*  kb = (bf16*)(ws + (1u << 20));             // 1 MB
    bf16*  vt = (bf16*)(ws + (2u << 20));             // 1 MB
    bf16*  wt = (bf16*)(ws + (3u << 20));             // 384 KB
    float* Op = (float*)(ws + (4u << 20));            // 8 MB
    float* lp = (float*)(ws + (12u << 20));           // 128 KB

    wt_prep<<<48, 256, 0, stream>>>(Wq, Wk, Wv, wt);
    qkv_proj_mfma<<<256, 256, 0, stream>>>(x, wt, qb, kb, vt);
    attn_kernel<<<512, 256, 0, stream>>>(qb, kb, vt, Op, lp);
    combine_attn<<<2048, 256, 0, stream>>>(Op, lp, out);
}